// Round 4
// baseline (377.020 us; speedup 1.0000x reference)
//
#include <hip/hip_runtime.h>

#define BB 16
#define CC 128
#define HH 112
#define NHH 4
#define WSZ 7
#define NN 49
#define SH 3

typedef _Float16 h8 __attribute__((ext_vector_type(8)));
typedef _Float16 h4 __attribute__((ext_vector_type(4)));
typedef float f4 __attribute__((ext_vector_type(4)));

__device__ __forceinline__ int rid3(int p) { return p < 105 ? 0 : (p < 109 ? 1 : 2); }

// XOR-swizzled element offset inside a row-major [rows][CH*8] fp16 tile.
// 16B chunks; chunk' = chunk ^ (row & (CH-1)). All h8 reads have j%8==0,
// h4 writes j%4==0 (j&7 in {0,4}) -> never cross a chunk.
#define SWZ(row, j, CH) ((row) * ((CH) * 8) + (((((j) >> 3) ^ (row)) & ((CH) - 1)) << 3) + ((j) & 7))

// LDS map (fp16 elems, 24576 total = 49152 B):
//  K  [4][64][32] @ 0      (8192)   CH=4
//  Q  [4][64][32] @ 8192   (8192)   CH=4
//  VT [4][32][64] @ 16384  (8192)   CH=8
// overlays:
//  P  [4][64][64] @ 0      (16384)  CH=8   (over K+Q, after B2)
//  O  [64][128]   @ 16384  (8192)   CH=16  (over VT, after B3)
//  Y  [64][128]   @ 0      (8192)   CH=16  (over P, after B4; layer0 only)
#define KB 0
#define QB 8192
#define VB 16384
#define PB 0
#define OB 16384
#define YB 0

// ---------------- patch embed: 4x4 stride-4 conv -> t0 (fp16, [B,H,W,C]) ----
__global__ __launch_bounds__(256) void conv_embed(const float* __restrict__ x,
    const float* __restrict__ cw, const float* __restrict__ cb, _Float16* __restrict__ t0) {
  __shared__ float xs[3][4][448];
  __shared__ float wT[48][128];
  __shared__ float cbs[128];
  int bid = blockIdx.x;
  int b = bid / HH, oh = bid % HH;
  int tid = threadIdx.x;
  for (int idx = tid; idx < 3 * 4 * 448; idx += 256) {
    int ch = idx / 1792;
    int r = (idx / 448) & 3;
    int col = idx % 448;
    xs[ch][r][col] = x[((b * 3 + ch) * 448 + (oh * 4 + r)) * 448 + col];
  }
  for (int idx = tid; idx < 6144; idx += 256) {
    int c = idx / 48, k = idx - c * 48;
    wT[k][c] = cw[idx];
  }
  if (tid < 128) cbs[tid] = cb[tid];
  __syncthreads();
  int c0 = (tid & 31) << 2;
  int gg = tid >> 5;
  for (int it = 0; it < 4; ++it) {
    int gw0 = it * 32 + gg * 4;
    if (gw0 >= HH) break;
    float acc[4][4] = {};
#pragma unroll
    for (int k = 0; k < 48; ++k) {
      int ch = k >> 4, r = (k >> 2) & 3, j = k & 3;
      float4 wv = *(const float4*)&wT[k][c0];
#pragma unroll
      for (int d = 0; d < 4; ++d) {
        float xv = xs[ch][r][(gw0 + d) * 4 + j];
        acc[d][0] = fmaf(xv, wv.x, acc[d][0]);
        acc[d][1] = fmaf(xv, wv.y, acc[d][1]);
        acc[d][2] = fmaf(xv, wv.z, acc[d][2]);
        acc[d][3] = fmaf(xv, wv.w, acc[d][3]);
      }
    }
    float4 bv = *(const float4*)&cbs[c0];
#pragma unroll
    for (int d = 0; d < 4; ++d) {
      int gw = gw0 + d;
      h4 o;
      o[0] = (_Float16)(acc[d][0] + bv.x); o[1] = (_Float16)(acc[d][1] + bv.y);
      o[2] = (_Float16)(acc[d][2] + bv.z); o[3] = (_Float16)(acc[d][3] + bv.w);
      *(h4*)&t0[((size_t)(b * HH + oh) * HH + gw) * CC + c0] = o;
    }
  }
}

// ---------------- prep: fp16 weights (Q-scale folded), scaled qb, bias table ----
// biasT layout: [layer][h][jt][it][lane][r] f32  (matches S^T C-fragment)
__global__ void prep(const float* __restrict__ qw, const float* __restrict__ qb,
                     const float* __restrict__ pw, const float* __restrict__ rpb,
                     _Float16* __restrict__ qwh, float* __restrict__ qbs,
                     _Float16* __restrict__ pwh, float* __restrict__ biasT) {
  const float scale = 0.17677669529663687f;  // 1/sqrt(32)
  int tid0 = blockIdx.x * blockDim.x + threadIdx.x;
  int stride = gridDim.x * blockDim.x;
  for (int idx = tid0; idx < 2 * 384 * 128; idx += stride) {
    int n = (idx >> 7) % 384;
    float v = qw[idx];
    if (n < 128) v *= scale;
    qwh[idx] = (_Float16)v;
  }
  for (int idx = tid0; idx < 2 * 384; idx += stride) {
    int n = idx % 384;
    float v = qb[idx];
    if (n < 128) v *= scale;
    qbs[idx] = v;
  }
  for (int idx = tid0; idx < 2 * 128 * 128; idx += stride)
    pwh[idx] = (_Float16)pw[idx];
  for (int idx = tid0; idx < 2 * 4 * 4 * 4 * 64 * 4; idx += stride) {
    int r = idx & 3;
    int lane = (idx >> 2) & 63;
    int it = (idx >> 8) & 3;
    int jt = (idx >> 10) & 3;
    int hh = (idx >> 12) & 3;
    int ll = idx >> 14;
    int i = it * 16 + (lane & 15);
    int j = jt * 16 + ((lane >> 4) * 4) + r;
    float v = 0.f;
    if (i < NN && j < NN) {
      int rel = ((i / 7 - j / 7) + 6) * 13 + ((i % 7 - j % 7) + 6);
      v = rpb[(ll * 169 + rel) * NHH + hh];
    }
    biasT[idx] = v;
  }
}

// ---------------- fused window layer (MFMA fp16, swizzled LDS) ----------------
// grid = 4096 (1 block = 1 window), 256 thr = 4 waves; wave = head in attn.
__global__ __launch_bounds__(256, 3) void swin_layer(
    const _Float16* __restrict__ tin, _Float16* __restrict__ toutB, float* __restrict__ outN,
    const _Float16* __restrict__ qwh, const float* __restrict__ qbs,
    const _Float16* __restrict__ pwh, const float* __restrict__ pb,
    const float* __restrict__ biasT, int shift, int writeN) {
  __shared__ _Float16 sm[24576];  // 49152 B -> 3 blocks/CU

  int tid = threadIdx.x;
  int wid = blockIdx.x;
  int b = wid >> 8;
  int wh = (wid >> 4) & 15, ww = wid & 15;
  int w = tid >> 6, l = tid & 63;
  int li = l & 15, lg = l >> 4;

  // per-lane rolled token pointers (tokens 49..63 read in-bounds garbage;
  // masked to zero influence downstream)
  const _Float16* tokp[4];
#pragma unroll
  for (int nt = 0; nt < 4; ++nt) {
    int n = nt * 16 + li;
    int gh = wh * WSZ + n / 7 + shift; if (gh >= HH) gh -= HH;
    int gw = ww * WSZ + n % 7 + shift; if (gw >= HH) gw -= HH;
    tokp[nt] = tin + ((size_t)(b * HH + gh) * HH + gw) * CC;
  }

  // ---- phase 2: QKV^T = Wqkv(384x128) . win^T ; win B-frags direct from global ----
  {
    f4 acc[6][4] = {};
#pragma unroll
    for (int ks = 0; ks < 4; ++ks) {
      h8 bW[4];
#pragma unroll
      for (int nt = 0; nt < 4; ++nt)
        bW[nt] = *(const h8*)(tokp[nt] + ks * 32 + lg * 8);
#pragma unroll
      for (int mi = 0; mi < 6; ++mi) {
        int mt = w * 6 + mi;
        h8 a = *(const h8*)(qwh + (size_t)(mt * 16 + li) * 128 + ks * 32 + lg * 8);
#pragma unroll
        for (int nt = 0; nt < 4; ++nt)
          acc[mi][nt] = __builtin_amdgcn_mfma_f32_16x16x32_f16(a, bW[nt], acc[mi][nt], 0, 0, 0);
      }
    }
    // scatter to K/Q/VT (swizzled)
#pragma unroll
    for (int mi = 0; mi < 6; ++mi) {
      int mt = w * 6 + mi;
      int dbase = mt * 16 + lg * 4;  // 0..383
      float4 bb = *(const float4*)&qbs[dbase];
#pragma unroll
      for (int nt = 0; nt < 4; ++nt) {
        int i = nt * 16 + li;  // token
        float v0 = acc[mi][nt][0] + bb.x, v1 = acc[mi][nt][1] + bb.y;
        float v2 = acc[mi][nt][2] + bb.z, v3 = acc[mi][nt][3] + bb.w;
        if (mt < 8) {  // Q
          int hq = dbase >> 5, dh = dbase & 31;
          h4 v = {(_Float16)v0, (_Float16)v1, (_Float16)v2, (_Float16)v3};
          *(h4*)&sm[QB + hq * 2048 + SWZ(i, dh, 4)] = v;
        } else if (mt < 16) {  // K
          int d = dbase - 128, hq = d >> 5, dh = d & 31;
          h4 v = {(_Float16)v0, (_Float16)v1, (_Float16)v2, (_Float16)v3};
          *(h4*)&sm[KB + hq * 2048 + SWZ(i, dh, 4)] = v;
        } else {  // V -> VT[d][token]
          int d = dbase - 256, hq = d >> 5, dh = d & 31;
          sm[VB + hq * 2048 + SWZ(dh + 0, i, 8)] = (_Float16)v0;
          sm[VB + hq * 2048 + SWZ(dh + 1, i, 8)] = (_Float16)v1;
          sm[VB + hq * 2048 + SWZ(dh + 2, i, 8)] = (_Float16)v2;
          sm[VB + hq * 2048 + SWZ(dh + 3, i, 8)] = (_Float16)v3;
        }
      }
    }
  }
  __syncthreads();  // B1

  // ---- phase 3: S^T = K . Q^T  (wave = head), bias + mask, softmax ----
  float inv[4];
  {
    int h = w;
    h8 aK[4], bQ[4];
#pragma unroll
    for (int jt = 0; jt < 4; ++jt)
      aK[jt] = *(const h8*)&sm[KB + h * 2048 + SWZ(jt * 16 + li, lg * 8, 4)];
#pragma unroll
    for (int it = 0; it < 4; ++it)
      bQ[it] = *(const h8*)&sm[QB + h * 2048 + SWZ(it * 16 + li, lg * 8, 4)];
    f4 s[4][4] = {};
#pragma unroll
    for (int jt = 0; jt < 4; ++jt)
#pragma unroll
      for (int it = 0; it < 4; ++it)
        s[jt][it] = __builtin_amdgcn_mfma_f32_16x16x32_f16(aK[jt], bQ[it], s[jt][it], 0, 0, 0);
    // bias (pre-arranged in C-layout) + j>=49 mask
    const float* bT = biasT + h * 4096;
#pragma unroll
    for (int jt = 0; jt < 4; ++jt)
#pragma unroll
      for (int it = 0; it < 4; ++it) {
        f4 bb = *(const f4*)&bT[(jt * 4 + it) * 256 + l * 4];
#pragma unroll
        for (int r = 0; r < 4; ++r) {
          int j = jt * 16 + lg * 4 + r;
          float v = s[jt][it][r] + bb[r];
          s[jt][it][r] = (j < NN) ? v : -1e30f;
        }
      }
    if (shift && (wh == 15 || ww == 15)) {
      int regi[4], regj[4][4];
#pragma unroll
      for (int it = 0; it < 4; ++it) {
        int i = it * 16 + li;
        regi[it] = rid3(wh * WSZ + i / 7) * 3 + rid3(ww * WSZ + i % 7);
      }
#pragma unroll
      for (int jt = 0; jt < 4; ++jt)
#pragma unroll
        for (int r = 0; r < 4; ++r) {
          int j = jt * 16 + lg * 4 + r;
          regj[jt][r] = rid3(wh * WSZ + j / 7) * 3 + rid3(ww * WSZ + j % 7);
        }
#pragma unroll
      for (int jt = 0; jt < 4; ++jt)
#pragma unroll
        for (int it = 0; it < 4; ++it)
#pragma unroll
          for (int r = 0; r < 4; ++r)
            if (regj[jt][r] != regi[it]) s[jt][it][r] -= 100.f;
    }
    __syncthreads();  // B2: all K/Q reads done -> P overlay safe

    // softmax over j (16 local values + 2 shuffles), write P[h][i][j] fp16
#pragma unroll
    for (int it = 0; it < 4; ++it) {
      float mx = -1e30f;
#pragma unroll
      for (int jt = 0; jt < 4; ++jt)
#pragma unroll
        for (int r = 0; r < 4; ++r) mx = fmaxf(mx, s[jt][it][r]);
      mx = fmaxf(mx, __shfl_xor(mx, 16));
      mx = fmaxf(mx, __shfl_xor(mx, 32));
      float sum = 0.f;
#pragma unroll
      for (int jt = 0; jt < 4; ++jt)
#pragma unroll
        for (int r = 0; r < 4; ++r) {
          float e = __expf(s[jt][it][r] - mx);
          s[jt][it][r] = e;
          sum += e;
        }
      sum += __shfl_xor(sum, 16);
      sum += __shfl_xor(sum, 32);
      inv[it] = 1.f / sum;
    }
#pragma unroll
    for (int it = 0; it < 4; ++it)
#pragma unroll
      for (int jt = 0; jt < 4; ++jt) {
        int i = it * 16 + li, j0 = jt * 16 + lg * 4;
        h4 v = {(_Float16)s[jt][it][0], (_Float16)s[jt][it][1],
                (_Float16)s[jt][it][2], (_Float16)s[jt][it][3]};
        *(h4*)&sm[PB + h * 4096 + SWZ(i, j0, 8)] = v;
      }
  }

  // ---- phase 4: O^T = V^T . P^T  (wave = head; P[h] is wave-local) ----
  {
    int h = w;
    h8 aV[2][2], bP[4][2];
#pragma unroll
    for (int mt = 0; mt < 2; ++mt)
#pragma unroll
      for (int ks = 0; ks < 2; ++ks)
        aV[mt][ks] = *(const h8*)&sm[VB + h * 2048 + SWZ(mt * 16 + li, ks * 32 + lg * 8, 8)];
#pragma unroll
    for (int nt = 0; nt < 4; ++nt)
#pragma unroll
      for (int ks = 0; ks < 2; ++ks)
        bP[nt][ks] = *(const h8*)&sm[PB + h * 4096 + SWZ(nt * 16 + li, ks * 32 + lg * 8, 8)];
    f4 o[2][4] = {};
#pragma unroll
    for (int ks = 0; ks < 2; ++ks)
#pragma unroll
      for (int mt = 0; mt < 2; ++mt)
#pragma unroll
        for (int nt = 0; nt < 4; ++nt)
          o[mt][nt] = __builtin_amdgcn_mfma_f32_16x16x32_f16(aV[mt][ks], bP[nt][ks], o[mt][nt], 0, 0, 0);
    __syncthreads();  // B3: all VT reads done -> O overlay safe
#pragma unroll
    for (int mt = 0; mt < 2; ++mt)
#pragma unroll
      for (int nt = 0; nt < 4; ++nt) {
        int i = nt * 16 + li;
        int d = h * 32 + mt * 16 + lg * 4;
        float is = inv[nt];
        h4 v = {(_Float16)(o[mt][nt][0] * is), (_Float16)(o[mt][nt][1] * is),
                (_Float16)(o[mt][nt][2] * is), (_Float16)(o[mt][nt][3] * is)};
        *(h4*)&sm[OB + SWZ(i, d, 16)] = v;
      }
  }
  __syncthreads();  // B4

  // ---- phase 5: y^T = pw(128x128) . O^T ----
  {
    f4 acc[2][4] = {};
#pragma unroll
    for (int ks = 0; ks < 4; ++ks) {
      h8 bO[4];
#pragma unroll
      for (int nt = 0; nt < 4; ++nt)
        bO[nt] = *(const h8*)&sm[OB + SWZ(nt * 16 + li, ks * 32 + lg * 8, 16)];
#pragma unroll
      for (int mi = 0; mi < 2; ++mi) {
        int mt = w * 2 + mi;
        h8 a = *(const h8*)(pwh + (size_t)(mt * 16 + li) * 128 + ks * 32 + lg * 8);
#pragma unroll
        for (int nt = 0; nt < 4; ++nt)
          acc[mi][nt] = __builtin_amdgcn_mfma_f32_16x16x32_f16(a, bO[nt], acc[mi][nt], 0, 0, 0);
      }
    }
    if (!writeN) {
      // layer 0: bounce y through LDS (Y over dead P), coalesced h8 stores
#pragma unroll
      for (int mi = 0; mi < 2; ++mi) {
        int dbase = (w * 2 + mi) * 16 + lg * 4;
        float4 bb = *(const float4*)&pb[dbase];
#pragma unroll
        for (int nt = 0; nt < 4; ++nt) {
          int i = nt * 16 + li;
          h4 v = {(_Float16)(acc[mi][nt][0] + bb.x), (_Float16)(acc[mi][nt][1] + bb.y),
                  (_Float16)(acc[mi][nt][2] + bb.z), (_Float16)(acc[mi][nt][3] + bb.w)};
          *(h4*)&sm[YB + SWZ(i, dbase, 16)] = v;
        }
      }
      __syncthreads();  // B5
      for (int cidx = tid; cidx < NN * 16; cidx += 256) {
        int tok = cidx >> 4, c = cidx & 15;
        h8 v = *(const h8*)&sm[YB + SWZ(tok, c * 8, 16)];
        int gh = wh * WSZ + tok / 7;
        int gw = ww * WSZ + tok % 7;
        *(h8*)&toutB[((size_t)(b * HH + gh) * HH + gw) * CC + c * 8] = v;
      }
    } else {
      // layer 1: direct scalar stores with fused NCHW transpose + roll
#pragma unroll
      for (int mi = 0; mi < 2; ++mi) {
        int dbase = (w * 2 + mi) * 16 + lg * 4;
        float4 bb = *(const float4*)&pb[dbase];
#pragma unroll
        for (int nt = 0; nt < 4; ++nt) {
          int i = nt * 16 + li;
          if (i < NN) {
            int gh = wh * WSZ + i / 7 + shift; if (gh >= HH) gh -= HH;
            int gw = ww * WSZ + i % 7 + shift; if (gw >= HH) gw -= HH;
            size_t base = ((size_t)(b * CC + dbase) * HH + gh) * HH + gw;
            outN[base] = acc[mi][nt][0] + bb.x;
            outN[base + (size_t)HH * HH] = acc[mi][nt][1] + bb.y;
            outN[base + (size_t)2 * HH * HH] = acc[mi][nt][2] + bb.z;
            outN[base + (size_t)3 * HH * HH] = acc[mi][nt][3] + bb.w;
          }
        }
      }
    }
  }
}

extern "C" void kernel_launch(void* const* d_in, const int* in_sizes, int n_in,
                              void* d_out, int out_size, void* d_ws, size_t ws_size,
                              hipStream_t stream) {
  const float* x = (const float*)d_in[0];
  const float* cw = (const float*)d_in[1];
  const float* cb = (const float*)d_in[2];
  const float* qkvw = (const float*)d_in[3];  // (2,384,128)
  const float* qkvb = (const float*)d_in[4];  // (2,384)
  const float* projw = (const float*)d_in[5]; // (2,128,128)
  const float* projb = (const float*)d_in[6]; // (2,128)
  const float* rpb = (const float*)d_in[7];   // (2,169,4)
  float* out = (float*)d_out;

  char* ws = (char*)d_ws;
  _Float16* t0 = (_Float16*)ws;                       // 16*112*112*128 fp16
  size_t off = (size_t)BB * HH * HH * CC * 2;
  _Float16* qwh = (_Float16*)(ws + off);  off += 2 * 384 * 128 * 2;
  _Float16* pwh = (_Float16*)(ws + off);  off += 2 * 128 * 128 * 2;
  float* qbs = (float*)(ws + off);        off += 2 * 384 * 4;
  float* biasT = (float*)(ws + off);      // 2*16384*4

  prep<<<224, 256, 0, stream>>>(qkvw, qkvb, projw, rpb, qwh, qbs, pwh, biasT);
  conv_embed<<<BB * HH, 256, 0, stream>>>(x, cw, cb, t0);

  // layer 0: no shift, in-place on t0 (windows partition tokens)
  swin_layer<<<4096, 256, 0, stream>>>(t0, t0, nullptr,
      qwh, qbs, pwh, projb, biasT, 0, 0);
  // layer 1: shift=3, fused NCHW transpose into d_out
  swin_layer<<<4096, 256, 0, stream>>>(t0, nullptr, out,
      qwh + 384 * 128, qbs + 384, pwh + 128 * 128, projb + 128,
      biasT + 16384, SH, 1);
}